// Round 4
// baseline (349.941 us; speedup 1.0000x reference)
//
#include <hip/hip_runtime.h>
#include <stdint.h>
#include <math.h>

// Problem constants (hard-coded in reference)
#define NBBOX 8192
#define FDIM  4096
#define H1DIM 64
#define H2DIM 32
#define NW    16

typedef __attribute__((ext_vector_type(8))) _Float16 f16x8;
typedef __attribute__((ext_vector_type(4))) float    f32x4;

typedef __attribute__((address_space(1))) void* gptr_t;
typedef __attribute__((address_space(3))) void* lptr_t;

// async global->LDS, 16B per lane; LDS dest is wave-uniform base + lane*16
__device__ __forceinline__ void g2l16(const void* g, void* l) {
    __builtin_amdgcn_global_load_lds((gptr_t)(uintptr_t)g,
                                     (lptr_t)(uint32_t)(uintptr_t)l,
                                     16, 0, 0);
}

__device__ __forceinline__ f16x8 cvt8(float4 a, float4 b) {
    f16x8 h;
    h[0] = (_Float16)a.x; h[1] = (_Float16)a.y; h[2] = (_Float16)a.z; h[3] = (_Float16)a.w;
    h[4] = (_Float16)b.x; h[5] = (_Float16)b.y; h[6] = (_Float16)b.z; h[7] = (_Float16)b.w;
    return h;
}

// ---------------- kernel 1: prep (gather+transpose W1[words] only) ----------------
// 16 words x 32 f-tiles = 512 blocks. x is NOT pre-converted: the GEMM converts
// f32->f16 in-register during A staging (saves the 192 MiB convert round-trip).
__global__ __launch_bounds__(256) void prep(
    const float* __restrict__ W1, const int* __restrict__ words,
    uint32_t* __restrict__ bth_u32)
{
    __shared__ uint32_t t[64 * 69];   // [c][f/2], pad 69 -> conflict-free
    const int tid = threadIdx.x;
    const int wi = blockIdx.x >> 5;
    const int ft = blockIdx.x & 31;
    const int f0 = ft * 128;
    const int w  = words[wi];
    const int c    = tid & 63;
    const int fgrp = tid >> 6;       // 0..3

    const float* src = W1 + ((size_t)w * FDIM + f0) * H1DIM + c;
#pragma unroll
    for (int p = 0; p < 16; ++p) {
        const int f = fgrp * 2 + p * 8;          // even f in 0..126
        float v0 = src[(size_t)f * H1DIM];        // coalesced (c contiguous)
        float v1 = src[(size_t)(f + 1) * H1DIM];
        union { _Float16 h[2]; uint32_t u; } pk;
        pk.h[0] = (_Float16)v0; pk.h[1] = (_Float16)v1;
        t[c * 69 + (f >> 1)] = pk.u;
    }
    __syncthreads();
#pragma unroll
    for (int p = 0; p < 16; ++p) {
        const int cc = p * 4 + (tid >> 6);
        const int fd = tid & 63;
        bth_u32[(size_t)(wi * 64 + cc) * (FDIM / 2) + ft * 64 + fd] = t[cc * 69 + fd];
    }
}

// ---------------- kernel 2: fused GEMM + tail MLP ----------------
// 128x128 tile, BK=64, 4 waves, 16x16x32 MFMA, one barrier per kt.
// Block map: mt = bx&63, nt = bx>>6 -> blocks sharing an A M-tile land on one XCD.
// A side: f32 x staged via regs with a ONE-BODY GAP (triple-stage):
//   body T:  ds_write A(T+1) from regs loaded at body T-1  (already drained: zero wait)
//            issue A(T+2) f32 loads into the other reg set  (drain at THIS body's barrier,
//            latency hidden under the MFMA phase — compiler can't sink past its use
//            which lies beyond the barrier; sched_barrier(0) pins it above the MFMAs)
//   Two static reg sets rA/rB, loop unrolled x2 (no runtime-indexed reg arrays).
// B side: g2l16 direct (linear dest, pre-swizzled per-lane global source).
// LDS layout (A and B): row r, 16B-chunk slot s at byte r*128 + s*16,
// slot s holds global chunk s ^ (r&7) -> bank-conflict-free ds_read_b128.
__global__ __launch_bounds__(256, 2) void gemm_fused(
    const float* __restrict__ x, const _Float16* __restrict__ bth,
    const float* __restrict__ b1, const int* __restrict__ words,
    const float* __restrict__ W2, const float* __restrict__ b2,
    const float* __restrict__ W3, const float* __restrict__ b3,
    float* __restrict__ sig)   // [NW][NBBOX]
{
    __shared__ __align__(16) char smem[65536];
    float* tile = (float*)smem;   // 64 KB, reused AFTER the final k-loop barrier

    const int mt   = blockIdx.x & 63;   // 64 M-tiles
    const int nt   = blockIdx.x >> 6;   // 8 N-tiles
    const int t    = threadIdx.x;
    const int w    = t >> 6;
    const int lane = t & 63;
    const int m0 = mt * 128, n0 = nt * 128;

    f32x4 acc[4][4] = {};

    // staging assignment: wave w handles rows w*32 .. w*32+31 (A and B)
    const int lr = lane >> 3;            // row within 8-row group (0..7)
    const int cg = lane & 7;             // 8-element k-chunk index (0..7)
    const float*    Ag = x   + (size_t)(m0 + w * 32 + lr) * FDIM + cg * 8;
    const _Float16* Bg = bth + (size_t)(n0 + w * 32 + lr) * FDIM + ((cg ^ lr) * 8);
    const int lwb = w * 4096;            // wave's LDS byte base (32 rows * 128 B)

    const int wm = w >> 1, wn = w & 1;
    const int ml = lane & 15;
    const int qw = lane >> 4;            // 16B chunk within 32-wide k panel

    float4 rA[8], rB[8];

#define STAGE_A_LOAD(R, KT) do { \
    _Pragma("unroll") \
    for (int c = 0; c < 4; ++c) { \
        const float* ap = Ag + (size_t)(c * 8) * FDIM + (size_t)(KT) * 64; \
        R[2 * c]     = *(const float4*)(ap); \
        R[2 * c + 1] = *(const float4*)(ap + 4); \
    } } while (0)

#define STAGE_B(KT, NB) do { \
    _Pragma("unroll") \
    for (int c = 0; c < 4; ++c) \
        g2l16(Bg + (size_t)(c * 8) * FDIM + (size_t)(KT) * 64, \
              smem + (NB) + 16384 + lwb + c * 1024); \
    } while (0)

#define WRITE_A(R, NB) do { \
    _Pragma("unroll") \
    for (int c = 0; c < 4; ++c) \
        *(f16x8*)(smem + (NB) + (w * 32 + c * 8 + lr) * 128 + ((cg ^ lr) * 16)) = \
            cvt8(R[2 * c], R[2 * c + 1]); \
    } while (0)

#define MFMA_PHASE(BUF) do { \
    const _Float16* Ab = (const _Float16*)(smem + (BUF)); \
    const _Float16* Bb = (const _Float16*)(smem + (BUF) + 16384); \
    _Pragma("unroll") \
    for (int s = 0; s < 2; ++s) { \
        f16x8 af[4], bfr[4]; \
        _Pragma("unroll") \
        for (int i = 0; i < 4; ++i) { \
            const int ra = wm * 64 + i * 16 + ml; \
            af[i] = *(const f16x8*)&Ab[ra * 64 + (((s * 4 + qw) ^ (ml & 7)) * 8)]; \
        } \
        _Pragma("unroll") \
        for (int j = 0; j < 4; ++j) { \
            const int rb = wn * 64 + j * 16 + ml; \
            bfr[j] = *(const f16x8*)&Bb[rb * 64 + (((s * 4 + qw) ^ (ml & 7)) * 8)]; \
        } \
        _Pragma("unroll") \
        for (int i = 0; i < 4; ++i) \
            _Pragma("unroll") \
            for (int j = 0; j < 4; ++j) \
                acc[i][j] = __builtin_amdgcn_mfma_f32_16x16x32_f16(af[i], bfr[j], acc[i][j], 0, 0, 0); \
    } } while (0)

    // ---- prologue: tile 0 into buf0; tile 1's A loads in flight ----
    STAGE_A_LOAD(rA, 0);          // A tile 0
    STAGE_B(0, 0);                // B tile 0 -> buf0
    WRITE_A(rA, 0);               // waits A0 loads (vmcnt<=4), writes buf0
    STAGE_A_LOAD(rB, 1);          // A tile 1 in flight (drained by barrier)
    __syncthreads();

    // invariant entering body T: set(T&1 ? rA : rB holds... ) even body writes rB, loads rA
    for (int kt = 0; kt < 62; kt += 2) {
        // body T=kt (even): compute buf0, prep buf1 with tile kt+1
        STAGE_A_LOAD(rA, kt + 2);
        STAGE_B(kt + 1, 32768);
        WRITE_A(rB, 32768);       // rB = A(kt+1), drained at previous barrier
        __builtin_amdgcn_sched_barrier(0);
        MFMA_PHASE(0);
        __syncthreads();
        // body T=kt+1 (odd): compute buf1, prep buf0 with tile kt+2
        STAGE_A_LOAD(rB, kt + 3);
        STAGE_B(kt + 2, 0);
        WRITE_A(rA, 0);           // rA = A(kt+2)
        __builtin_amdgcn_sched_barrier(0);
        MFMA_PHASE(32768);
        __syncthreads();
    }
    // T=62: compute buf0, prep buf1 with tile 63 (no further A loads)
    STAGE_B(63, 32768);
    WRITE_A(rB, 32768);           // rB = A(63), loaded at T=61
    __builtin_amdgcn_sched_barrier(0);
    MFMA_PHASE(0);
    __syncthreads();
    // T=63: compute buf1
    MFMA_PHASE(32768);
    __syncthreads();              // guards As/Bs -> tile reuse in epilogue

#undef STAGE_A_LOAD
#undef STAGE_B
#undef WRITE_A
#undef MFMA_PHASE

    // ---- epilogue: bias+relu into wave-private swizzled LDS tile ----
    // C/D layout: col=lane&15, row=quad*4+reg  [m89-verified]
    const int q  = lane >> 4;
    const int wi = nt * 2 + wn;                                   // word slot 0..15
    const int wv = __builtin_amdgcn_readfirstlane(words[wi]);     // force SGPR
    float* tw = tile + w * 4096;                                  // [64 rows][64 k]

#pragma unroll
    for (int j = 0; j < 4; ++j) {
        const int col = j * 16 + ml;                              // k within word, 0..63
        const float bias = b1[wv * H1DIM + col];
        const int c = col >> 2, e = col & 3;
#pragma unroll
        for (int i = 0; i < 4; ++i) {
#pragma unroll
            for (int r = 0; r < 4; ++r) {
                const int row = i * 16 + q * 4 + r;               // local row 0..63
                const int pos = ((c + row) & 7) | (c & 8);        // chunk swizzle
                float v = acc[i][j][r] + bias;
                tw[row * 64 + pos * 4 + e] = v > 0.f ? v : 0.f;
            }
        }
    }
    // wave-private LDS: no barrier needed (compiler inserts lgkmcnt waits)

    // ---- layer 2+3 + sigmoid, one row per lane ----
    const float* W2w = W2 + (size_t)wv * (H1DIM * H2DIM);
    float a2[H2DIM];
#pragma unroll
    for (int j = 0; j < H2DIM; ++j) a2[j] = 0.f;

#pragma unroll
    for (int c2 = 0; c2 < 16; ++c2) {
        const int pos = ((c2 + lane) & 7) | (c2 & 8);
        f32x4 h = *(const f32x4*)&tw[lane * 64 + pos * 4];
#pragma unroll
        for (int kk = 0; kk < 4; ++kk) {
            const float hv = h[kk];
            const int k = c2 * 4 + kk;
#pragma unroll
            for (int j = 0; j < H2DIM; ++j)
                a2[j] = fmaf(hv, W2w[k * H2DIM + j], a2[j]);
        }
    }

    float logit = b3[wv];
#pragma unroll
    for (int j = 0; j < H2DIM; ++j) {
        float h2 = a2[j] + b2[wv * H2DIM + j];
        h2 = h2 > 0.f ? h2 : 0.f;
        logit = fmaf(h2, W3[wv * H2DIM + j], logit);
    }
    sig[(size_t)wi * NBBOX + m0 + wm * 64 + lane] = 1.f / (1.f + expf(-logit));
}

// ---------------- kernel 3: product over words ----------------
__global__ void prod_k(const float* __restrict__ sig, float* __restrict__ out) {
    const int r = blockIdx.x * 256 + threadIdx.x;
    float p = 1.f;
#pragma unroll
    for (int wi = 0; wi < NW; ++wi) p *= sig[(size_t)wi * NBBOX + r];
    out[r] = p;
}

extern "C" void kernel_launch(void* const* d_in, const int* in_sizes, int n_in,
                              void* d_out, int out_size, void* d_ws, size_t ws_size,
                              hipStream_t stream)
{
    const float* x   = (const float*)d_in[1];
    const int* words = (const int*)  d_in[2];
    const float* W1  = (const float*)d_in[3];
    const float* b1  = (const float*)d_in[4];
    const float* W2  = (const float*)d_in[5];
    const float* b2  = (const float*)d_in[6];
    const float* W3  = (const float*)d_in[7];
    const float* b3  = (const float*)d_in[8];
    float* out = (float*)d_out;

    char* ws = (char*)d_ws;
    _Float16* bth = (_Float16*)(ws);                 // 1024*4096*2 = 8 MiB
    float*    sig = (float*)   (ws + 8388608);       // 16*8192*4   = 512 KiB

    prep<<<512, 256, 0, stream>>>(W1, words, (uint32_t*)bth);
    gemm_fused<<<512, 256, 0, stream>>>(x, bth, b1, words, W2, b2, W3, b3, sig);
    prod_k<<<NBBOX / 256, 256, 0, stream>>>(sig, out);
}

// Round 6
// 339.765 us; speedup vs baseline: 1.0300x; 1.0300x over previous
//
#include <hip/hip_runtime.h>
#include <stdint.h>
#include <math.h>

// Problem constants (hard-coded in reference)
#define NBBOX 8192
#define FDIM  4096
#define H1DIM 64
#define H2DIM 32
#define NW    16

typedef __attribute__((ext_vector_type(8))) _Float16 f16x8;
typedef __attribute__((ext_vector_type(4))) _Float16 f16x4;
typedef __attribute__((ext_vector_type(4))) float    f32x4;

typedef __attribute__((address_space(1))) void* gptr_t;
typedef __attribute__((address_space(3))) void* lptr_t;

// async global->LDS, 16B per lane; LDS dest is wave-uniform base + lane*16
__device__ __forceinline__ void g2l16(const void* g, void* l) {
    __builtin_amdgcn_global_load_lds((gptr_t)(uintptr_t)g,
                                     (lptr_t)(uint32_t)(uintptr_t)l,
                                     16, 0, 0);
}

// ---------------- kernel 1: prep (gather+transpose W1[words] only) ----------------
// 16 words x 32 f-tiles = 512 blocks. x is NOT pre-converted: the GEMM converts
// f32->f16 in-register during A staging (saves the 192 MiB convert round-trip).
__global__ __launch_bounds__(256) void prep(
    const float* __restrict__ W1, const int* __restrict__ words,
    uint32_t* __restrict__ bth_u32)
{
    __shared__ uint32_t t[64 * 69];   // [c][f/2], pad 69 -> conflict-free
    const int tid = threadIdx.x;
    const int wi = blockIdx.x >> 5;
    const int ft = blockIdx.x & 31;
    const int f0 = ft * 128;
    const int w  = words[wi];
    const int c    = tid & 63;
    const int fgrp = tid >> 6;       // 0..3

    const float* src = W1 + ((size_t)w * FDIM + f0) * H1DIM + c;
#pragma unroll
    for (int p = 0; p < 16; ++p) {
        const int f = fgrp * 2 + p * 8;          // even f in 0..126
        float v0 = src[(size_t)f * H1DIM];        // coalesced (c contiguous)
        float v1 = src[(size_t)(f + 1) * H1DIM];
        union { _Float16 h[2]; uint32_t u; } pk;
        pk.h[0] = (_Float16)v0; pk.h[1] = (_Float16)v1;
        t[c * 69 + (f >> 1)] = pk.u;
    }
    __syncthreads();
#pragma unroll
    for (int p = 0; p < 16; ++p) {
        const int cc = p * 4 + (tid >> 6);
        const int fd = tid & 63;
        bth_u32[(size_t)(wi * 64 + cc) * (FDIM / 2) + ft * 64 + fd] = t[cc * 69 + fd];
    }
}

// ---------------- kernel 2: fused GEMM + tail MLP ----------------
// 128x128 tile, BK=64, 4 waves, 16x16x32 MFMA, one barrier per kt.
// Block map: mt = bx&63, nt = bx>>6 -> blocks sharing an A M-tile land on one XCD.
// A side: f32 x staged via regs, FULLY COALESCED: 16 lanes per row (one float4 per
//   lane = 256B contiguous per row, 16 fully-used 64B lines per instruction).
//   r3/r4's 32B-strided dwordx4 pattern half-used every line and doubled the
//   TA line-request rate -> 2x body time. Triple-stage kept (one-body gap).
// B side: g2l16 direct (linear dest, pre-swizzled per-lane global source).
// LDS layout (A and B): row r, 16B-chunk slot s at byte r*128 + s*16,
// slot s holds global chunk s ^ (r&7) -> bank-conflict-free ds_read_b128.
__global__ __launch_bounds__(256, 2) void gemm_fused(
    const float* __restrict__ x, const _Float16* __restrict__ bth,
    const float* __restrict__ b1, const int* __restrict__ words,
    const float* __restrict__ W2, const float* __restrict__ b2,
    const float* __restrict__ W3, const float* __restrict__ b3,
    float* __restrict__ sig)   // [NW][NBBOX]
{
    __shared__ __align__(16) char smem[65536];
    float* tile = (float*)smem;   // 64 KB, reused AFTER the final k-loop barrier

    const int mt   = blockIdx.x & 63;   // 64 M-tiles
    const int nt   = blockIdx.x >> 6;   // 8 N-tiles
    const int t    = threadIdx.x;
    const int w    = t >> 6;
    const int lane = t & 63;
    const int m0 = mt * 128, n0 = nt * 128;

    f32x4 acc[4][4] = {};

    // ---- A staging layout: 16 lanes/row, fully coalesced ----
    const int r4  = lane >> 4;           // 0..3 : row within 4-row group
    const int c16 = lane & 15;           // 0..15: float4 (16B) chunk within 256B row
    const float* Ag = x + (size_t)(m0 + w * 32 + r4) * FDIM + c16 * 4;
    // ---- B staging layout: 8 lanes/row (f16 rows are 128B) ----
    const int lr = lane >> 3;            // row within 8-row group (0..7)
    const int cg = lane & 7;             // 16B f16-chunk index (0..7)
    const _Float16* Bg = bth + (size_t)(n0 + w * 32 + lr) * FDIM + ((cg ^ lr) * 8);
    const int lwb = w * 4096;            // wave's LDS byte base (32 rows * 128 B)

    const int wm = w >> 1, wn = w & 1;
    const int ml = lane & 15;
    const int qw = lane >> 4;            // 16B chunk within 32-wide k panel

    float4 rA[8], rB[8];

#define STAGE_A_LOAD(R, KT) do { \
    _Pragma("unroll") \
    for (int p = 0; p < 8; ++p) \
        R[p] = *(const float4*)(Ag + (size_t)(p * 4) * FDIM + (size_t)(KT) * 64); \
    } while (0)

#define STAGE_B(KT, NB) do { \
    _Pragma("unroll") \
    for (int c = 0; c < 4; ++c) \
        g2l16(Bg + (size_t)(c * 8) * FDIM + (size_t)(KT) * 64, \
              smem + (NB) + 16384 + lwb + c * 1024); \
    } while (0)

// lane holds k-chunk c16 (4 floats) of tile-row (w*32 + p*4 + r4).
// f16 16B-slot = (c16>>1) ^ (row&7); half (c16&1) within the slot.
#define WRITE_A(R, NB) do { \
    _Pragma("unroll") \
    for (int p = 0; p < 8; ++p) { \
        const int rowl = p * 4 + r4; \
        const int off = (NB) + (w * 32 + rowl) * 128 \
                      + (((c16 >> 1) ^ (rowl & 7)) * 16) + ((c16 & 1) * 8); \
        f16x4 h; \
        h[0] = (_Float16)R[p].x; h[1] = (_Float16)R[p].y; \
        h[2] = (_Float16)R[p].z; h[3] = (_Float16)R[p].w; \
        *(f16x4*)(smem + off) = h; \
    } } while (0)

#define MFMA_PHASE(BUF) do { \
    const _Float16* Ab = (const _Float16*)(smem + (BUF)); \
    const _Float16* Bb = (const _Float16*)(smem + (BUF) + 16384); \
    _Pragma("unroll") \
    for (int s = 0; s < 2; ++s) { \
        f16x8 af[4], bfr[4]; \
        _Pragma("unroll") \
        for (int i = 0; i < 4; ++i) { \
            const int ra = wm * 64 + i * 16 + ml; \
            af[i] = *(const f16x8*)&Ab[ra * 64 + (((s * 4 + qw) ^ (ml & 7)) * 8)]; \
        } \
        _Pragma("unroll") \
        for (int j = 0; j < 4; ++j) { \
            const int rb = wn * 64 + j * 16 + ml; \
            bfr[j] = *(const f16x8*)&Bb[rb * 64 + (((s * 4 + qw) ^ (ml & 7)) * 8)]; \
        } \
        _Pragma("unroll") \
        for (int i = 0; i < 4; ++i) \
            _Pragma("unroll") \
            for (int j = 0; j < 4; ++j) \
                acc[i][j] = __builtin_amdgcn_mfma_f32_16x16x32_f16(af[i], bfr[j], acc[i][j], 0, 0, 0); \
    } } while (0)

    // ---- prologue: tile 0 into buf0; tile 1's A loads in flight ----
    STAGE_A_LOAD(rA, 0);          // A tile 0
    STAGE_B(0, 0);                // B tile 0 -> buf0
    WRITE_A(rA, 0);               // waits A0 loads, writes buf0
    STAGE_A_LOAD(rB, 1);          // A tile 1 in flight (drained by barrier)
    __syncthreads();

    for (int kt = 0; kt < 62; kt += 2) {
        // body T=kt (even): compute buf0, prep buf1 with tile kt+1
        STAGE_A_LOAD(rA, kt + 2);
        STAGE_B(kt + 1, 32768);
        WRITE_A(rB, 32768);       // rB = A(kt+1), drained at previous barrier
        __builtin_amdgcn_sched_barrier(0);
        MFMA_PHASE(0);
        __syncthreads();
        // body T=kt+1 (odd): compute buf1, prep buf0 with tile kt+2
        STAGE_A_LOAD(rB, kt + 3);
        STAGE_B(kt + 2, 0);
        WRITE_A(rA, 0);           // rA = A(kt+2)
        __builtin_amdgcn_sched_barrier(0);
        MFMA_PHASE(32768);
        __syncthreads();
    }
    // T=62: compute buf0, prep buf1 with tile 63 (no further A loads)
    STAGE_B(63, 32768);
    WRITE_A(rB, 32768);           // rB = A(63), loaded at T=61
    __builtin_amdgcn_sched_barrier(0);
    MFMA_PHASE(0);
    __syncthreads();
    // T=63: compute buf1
    MFMA_PHASE(32768);
    __syncthreads();              // guards As/Bs -> tile reuse in epilogue

#undef STAGE_A_LOAD
#undef STAGE_B
#undef WRITE_A
#undef MFMA_PHASE

    // ---- epilogue: bias+relu into wave-private swizzled LDS tile ----
    // C/D layout: col=lane&15, row=quad*4+reg  [m89-verified]
    const int q  = lane >> 4;
    const int wi = nt * 2 + wn;                                   // word slot 0..15
    const int wv = __builtin_amdgcn_readfirstlane(words[wi]);     // force SGPR
    float* tw = tile + w * 4096;                                  // [64 rows][64 k]

#pragma unroll
    for (int j = 0; j < 4; ++j) {
        const int col = j * 16 + ml;                              // k within word, 0..63
        const float bias = b1[wv * H1DIM + col];
        const int c = col >> 2, e = col & 3;
#pragma unroll
        for (int i = 0; i < 4; ++i) {
#pragma unroll
            for (int r = 0; r < 4; ++r) {
                const int row = i * 16 + q * 4 + r;               // local row 0..63
                const int pos = ((c + row) & 7) | (c & 8);        // chunk swizzle
                float v = acc[i][j][r] + bias;
                tw[row * 64 + pos * 4 + e] = v > 0.f ? v : 0.f;
            }
        }
    }
    // wave-private LDS: no barrier needed (compiler inserts lgkmcnt waits)

    // ---- layer 2+3 + sigmoid, one row per lane ----
    const float* W2w = W2 + (size_t)wv * (H1DIM * H2DIM);
    float a2[H2DIM];
#pragma unroll
    for (int j = 0; j < H2DIM; ++j) a2[j] = 0.f;

#pragma unroll
    for (int c2 = 0; c2 < 16; ++c2) {
        const int pos = ((c2 + lane) & 7) | (c2 & 8);
        f32x4 h = *(const f32x4*)&tw[lane * 64 + pos * 4];
#pragma unroll
        for (int kk = 0; kk < 4; ++kk) {
            const float hv = h[kk];
            const int k = c2 * 4 + kk;
#pragma unroll
            for (int j = 0; j < H2DIM; ++j)
                a2[j] = fmaf(hv, W2w[k * H2DIM + j], a2[j]);
        }
    }

    float logit = b3[wv];
#pragma unroll
    for (int j = 0; j < H2DIM; ++j) {
        float h2 = a2[j] + b2[wv * H2DIM + j];
        h2 = h2 > 0.f ? h2 : 0.f;
        logit = fmaf(h2, W3[wv * H2DIM + j], logit);
    }
    sig[(size_t)wi * NBBOX + m0 + wm * 64 + lane] = 1.f / (1.f + expf(-logit));
}

// ---------------- kernel 3: product over words ----------------
__global__ void prod_k(const float* __restrict__ sig, float* __restrict__ out) {
    const int r = blockIdx.x * 256 + threadIdx.x;
    float p = 1.f;
#pragma unroll
    for (int wi = 0; wi < NW; ++wi) p *= sig[(size_t)wi * NBBOX + r];
    out[r] = p;
}

extern "C" void kernel_launch(void* const* d_in, const int* in_sizes, int n_in,
                              void* d_out, int out_size, void* d_ws, size_t ws_size,
                              hipStream_t stream)
{
    const float* x   = (const float*)d_in[1];
    const int* words = (const int*)  d_in[2];
    const float* W1  = (const float*)d_in[3];
    const float* b1  = (const float*)d_in[4];
    const float* W2  = (const float*)d_in[5];
    const float* b2  = (const float*)d_in[6];
    const float* W3  = (const float*)d_in[7];
    const float* b3  = (const float*)d_in[8];
    float* out = (float*)d_out;

    char* ws = (char*)d_ws;
    _Float16* bth = (_Float16*)(ws);                 // 1024*4096*2 = 8 MiB
    float*    sig = (float*)   (ws + 8388608);       // 16*8192*4   = 512 KiB

    prep<<<512, 256, 0, stream>>>(W1, words, (uint32_t*)bth);
    gemm_fused<<<512, 256, 0, stream>>>(x, bth, b1, words, W2, b2, W3, b3, sig);
    prod_k<<<NBBOX / 256, 256, 0, stream>>>(sig, out);
}

// Round 7
// 332.418 us; speedup vs baseline: 1.0527x; 1.0221x over previous
//
#include <hip/hip_runtime.h>
#include <stdint.h>
#include <math.h>

// Problem constants (hard-coded in reference)
#define NBBOX 8192
#define FDIM  4096
#define H1DIM 64
#define H2DIM 32
#define NW    16

typedef __attribute__((ext_vector_type(8))) _Float16 f16x8;
typedef __attribute__((ext_vector_type(4))) float    f32x4;

typedef __attribute__((address_space(1))) void* gptr_t;
typedef __attribute__((address_space(3))) void* lptr_t;

// async global->LDS, 16B per lane; LDS dest is wave-uniform base + lane*16
__device__ __forceinline__ void g2l16(const void* g, void* l) {
    __builtin_amdgcn_global_load_lds((gptr_t)(uintptr_t)g,
                                     (lptr_t)(uint32_t)(uintptr_t)l,
                                     16, 0, 0);
}

// ---------------- kernel 1: prep (gather+transpose W1[words] only) ----------------
// 16 words x 32 f-tiles = 512 blocks. x is NOT pre-converted: the GEMM stages
// f32 x directly via global_load_lds and converts f32->f16 during the LDS->reg
// fragment read (r3-r6 showed reg->cvt->ds_write staging costs 2x; g2l16 is the
// only fast staging path on this structure [m151]).
__global__ __launch_bounds__(256) void prep(
    const float* __restrict__ W1, const int* __restrict__ words,
    uint32_t* __restrict__ bth_u32)
{
    __shared__ uint32_t t[64 * 69];   // [c][f/2], pad 69 -> conflict-free
    const int tid = threadIdx.x;
    const int wi = blockIdx.x >> 5;
    const int ft = blockIdx.x & 31;
    const int f0 = ft * 128;
    const int w  = words[wi];
    const int c    = tid & 63;
    const int fgrp = tid >> 6;       // 0..3

    const float* src = W1 + ((size_t)w * FDIM + f0) * H1DIM + c;
#pragma unroll
    for (int p = 0; p < 16; ++p) {
        const int f = fgrp * 2 + p * 8;          // even f in 0..126
        float v0 = src[(size_t)f * H1DIM];        // coalesced (c contiguous)
        float v1 = src[(size_t)(f + 1) * H1DIM];
        union { _Float16 h[2]; uint32_t u; } pk;
        pk.h[0] = (_Float16)v0; pk.h[1] = (_Float16)v1;
        t[c * 69 + (f >> 1)] = pk.u;
    }
    __syncthreads();
#pragma unroll
    for (int p = 0; p < 16; ++p) {
        const int cc = p * 4 + (tid >> 6);
        const int fd = tid & 63;
        bth_u32[(size_t)(wi * 64 + cc) * (FDIM / 2) + ft * 64 + fd] = t[cc * 69 + fd];
    }
}

// ---------------- kernel 2: fused GEMM + tail MLP ----------------
// 128x128 tile, 4 waves, 16x16x32 MFMA.
// Block map: mt = bx&63, nt = bx>>6 -> blocks sharing an A M-tile land on one XCD.
// A: staged as RAW F32 via g2l16 (K-step 32, dbuf 2x16KB at +0/+16384); converted
//    f32->f16 at fragment-read time (2x ds_read_b128 + 8 cvt per frag).
// B: f16 via g2l16 in K=64 tiles staged every other step (dbuf 2x16KB at
//    +32768/+49152) — identical addressing to the proven r2 path.
// One barrier per K32 step (128 total).
// LDS swizzle (both): row r, 16B-chunk slot s at byte r*128 + s*16; slot s holds
// global chunk s ^ (r&7)  -> bank-conflict-free ds_read_b128 (A reads 2-way=free).
__global__ __launch_bounds__(256, 2) void gemm_fused(
    const float* __restrict__ x, const _Float16* __restrict__ bth,
    const float* __restrict__ b1, const int* __restrict__ words,
    const float* __restrict__ W2, const float* __restrict__ b2,
    const float* __restrict__ W3, const float* __restrict__ b3,
    float* __restrict__ sig)   // [NW][NBBOX]
{
    __shared__ __align__(16) char smem[65536];
    float* tile = (float*)smem;   // 64 KB, reused AFTER the final k-loop barrier

    const int mt   = blockIdx.x & 63;   // 64 M-tiles
    const int nt   = blockIdx.x >> 6;   // 8 N-tiles
    const int t    = threadIdx.x;
    const int w    = t >> 6;
    const int lane = t & 63;
    const int m0 = mt * 128, n0 = nt * 128;

    f32x4 acc[4][4] = {};

    // staging: wave w handles rows w*32 .. w*32+31; 8 lanes/row, source pre-swizzled
    const int lr = lane >> 3;            // row within 8-row group (0..7)
    const int cg = lane & 7;             // dest 16B-chunk slot (0..7)
    const float*    Ag = x   + (size_t)(m0 + w * 32 + lr) * FDIM + ((cg ^ lr) * 4);
    const _Float16* Bg = bth + (size_t)(n0 + w * 32 + lr) * FDIM + ((cg ^ lr) * 8);
    const int lwb = w * 4096;            // wave's LDS byte base (32 rows * 128 B)

    const int wm = w >> 1, wn = w & 1;
    const int ml = lane & 15;
    const int qw = lane >> 4;            // 0..3
    const int x7 = ml & 7;

#define STAGE_A(U, AB) do { \
    _Pragma("unroll") \
    for (int c = 0; c < 4; ++c) \
        g2l16(Ag + (size_t)(c * 8) * FDIM + (size_t)(U) * 32, \
              smem + (AB) + lwb + c * 1024); \
    } while (0)

#define STAGE_B(V, BB) do { \
    _Pragma("unroll") \
    for (int c = 0; c < 4; ++c) \
        g2l16(Bg + (size_t)(c * 8) * FDIM + (size_t)(V) * 64, \
              smem + (BB) + lwb + c * 1024); \
    } while (0)

// One K=32 step: A from f32 buf AB (cvt on read), B from f16 buf BB half HALF.
#define STEP(AB, BB, HALF) do { \
    const char* Abp = smem + (AB); \
    const char* Bbp = smem + (BB); \
    f16x8 af[4], bf[4]; \
    _Pragma("unroll") \
    for (int i = 0; i < 4; ++i) { \
        const int ra = wm * 64 + i * 16 + ml; \
        f32x4 lo = *(const f32x4*)(Abp + ra * 128 + (((2 * qw    ) ^ x7) * 16)); \
        f32x4 hi = *(const f32x4*)(Abp + ra * 128 + (((2 * qw + 1) ^ x7) * 16)); \
        f16x8 h; \
        h[0] = (_Float16)lo[0]; h[1] = (_Float16)lo[1]; \
        h[2] = (_Float16)lo[2]; h[3] = (_Float16)lo[3]; \
        h[4] = (_Float16)hi[0]; h[5] = (_Float16)hi[1]; \
        h[6] = (_Float16)hi[2]; h[7] = (_Float16)hi[3]; \
        af[i] = h; \
    } \
    _Pragma("unroll") \
    for (int j = 0; j < 4; ++j) { \
        const int rb = wn * 64 + j * 16 + ml; \
        bf[j] = *(const f16x8*)(Bbp + rb * 128 + ((((HALF) * 4 + qw) ^ x7) * 16)); \
    } \
    _Pragma("unroll") \
    for (int i = 0; i < 4; ++i) \
        _Pragma("unroll") \
        for (int j = 0; j < 4; ++j) \
            acc[i][j] = __builtin_amdgcn_mfma_f32_16x16x32_f16(af[i], bf[j], acc[i][j], 0, 0, 0); \
    } while (0)

    // prologue: A step 0 -> Ab0, B tile 0 -> Bb0
    STAGE_A(0, 0);
    STAGE_B(0, 32768);
    __syncthreads();

    for (int v = 0; v < 63; ++v) {
        const int bb  = 32768 + (v & 1) * 16384;         // current B tile
        const int bbn = 32768 + ((v + 1) & 1) * 16384;   // next B tile
        // even step u=2v: compute Ab0 x Bb(half0); stage A(2v+1)->Ab1, B(v+1)->bbn
        STAGE_A(2 * v + 1, 16384);
        STAGE_B(v + 1, bbn);
        STEP(0, bb, 0);
        __syncthreads();
        // odd step u=2v+1: compute Ab1 x Bb(half1); stage A(2v+2)->Ab0
        STAGE_A(2 * v + 2, 0);
        STEP(16384, bb, 1);
        __syncthreads();
    }
    // v=63 (B tile 63 in buf +49152, staged at v=62)
    STAGE_A(127, 16384);
    STEP(0, 49152, 0);
    __syncthreads();
    STEP(16384, 49152, 1);
    __syncthreads();              // guards bufs -> tile reuse in epilogue

#undef STAGE_A
#undef STAGE_B
#undef STEP

    // ---- epilogue: bias+relu into wave-private swizzled LDS tile ----
    // C/D layout: col=lane&15, row=quad*4+reg  [m89-verified]
    const int q  = lane >> 4;
    const int wi = nt * 2 + wn;                                   // word slot 0..15
    const int wv = __builtin_amdgcn_readfirstlane(words[wi]);     // force SGPR
    float* tw = tile + w * 4096;                                  // [64 rows][64 k]

#pragma unroll
    for (int j = 0; j < 4; ++j) {
        const int col = j * 16 + ml;                              // k within word, 0..63
        const float bias = b1[wv * H1DIM + col];
        const int c = col >> 2, e = col & 3;
#pragma unroll
        for (int i = 0; i < 4; ++i) {
#pragma unroll
            for (int r = 0; r < 4; ++r) {
                const int row = i * 16 + q * 4 + r;               // local row 0..63
                const int pos = ((c + row) & 7) | (c & 8);        // chunk swizzle
                float v = acc[i][j][r] + bias;
                tw[row * 64 + pos * 4 + e] = v > 0.f ? v : 0.f;
            }
        }
    }
    // wave-private LDS: no barrier needed (compiler inserts lgkmcnt waits)

    // ---- layer 2+3 + sigmoid, one row per lane ----
    const float* W2w = W2 + (size_t)wv * (H1DIM * H2DIM);
    float a2[H2DIM];
#pragma unroll
    for (int j = 0; j < H2DIM; ++j) a2[j] = 0.f;

#pragma unroll
    for (int c2 = 0; c2 < 16; ++c2) {
        const int pos = ((c2 + lane) & 7) | (c2 & 8);
        f32x4 h = *(const f32x4*)&tw[lane * 64 + pos * 4];
#pragma unroll
        for (int kk = 0; kk < 4; ++kk) {
            const float hv = h[kk];
            const int k = c2 * 4 + kk;
#pragma unroll
            for (int j = 0; j < H2DIM; ++j)
                a2[j] = fmaf(hv, W2w[k * H2DIM + j], a2[j]);
        }
    }

    float logit = b3[wv];
#pragma unroll
    for (int j = 0; j < H2DIM; ++j) {
        float h2 = a2[j] + b2[wv * H2DIM + j];
        h2 = h2 > 0.f ? h2 : 0.f;
        logit = fmaf(h2, W3[wv * H2DIM + j], logit);
    }
    sig[(size_t)wi * NBBOX + m0 + wm * 64 + lane] = 1.f / (1.f + expf(-logit));
}

// ---------------- kernel 3: product over words ----------------
__global__ void prod_k(const float* __restrict__ sig, float* __restrict__ out) {
    const int r = blockIdx.x * 256 + threadIdx.x;
    float p = 1.f;
#pragma unroll
    for (int wi = 0; wi < NW; ++wi) p *= sig[(size_t)wi * NBBOX + r];
    out[r] = p;
}

extern "C" void kernel_launch(void* const* d_in, const int* in_sizes, int n_in,
                              void* d_out, int out_size, void* d_ws, size_t ws_size,
                              hipStream_t stream)
{
    const float* x   = (const float*)d_in[1];
    const int* words = (const int*)  d_in[2];
    const float* W1  = (const float*)d_in[3];
    const float* b1  = (const float*)d_in[4];
    const float* W2  = (const float*)d_in[5];
    const float* b2  = (const float*)d_in[6];
    const float* W3  = (const float*)d_in[7];
    const float* b3  = (const float*)d_in[8];
    float* out = (float*)d_out;

    char* ws = (char*)d_ws;
    _Float16* bth = (_Float16*)(ws);                 // 1024*4096*2 = 8 MiB
    float*    sig = (float*)   (ws + 8388608);       // 16*8192*4   = 512 KiB

    prep<<<512, 256, 0, stream>>>(W1, words, (uint32_t*)bth);
    gemm_fused<<<512, 256, 0, stream>>>(x, bth, b1, words, W2, b2, W3, b3, sig);
    prod_k<<<NBBOX / 256, 256, 0, stream>>>(sig, out);
}